// Round 2
// baseline (1080.128 us; speedup 1.0000x reference)
//
#include <hip/hip_runtime.h>
#include <hip/hip_bf16.h>
#include <stdint.h>

typedef __bf16 bf16;
typedef __bf16 bf16x8 __attribute__((ext_vector_type(8)));
typedef __bf16 bf16x4v __attribute__((ext_vector_type(4)));
typedef float f32x4 __attribute__((ext_vector_type(4)));

#define AS1 __attribute__((address_space(1)))
#define AS3 __attribute__((address_space(3)))

__device__ __forceinline__ void g2lds16(const bf16* g, bf16* l) {
  // global -> LDS async copy, 16 B/lane. LDS dest must be wave-uniform base + lane*16.
  __builtin_amdgcn_global_load_lds((AS1 void*)(uintptr_t)g, (AS3 void*)l, 16, 0, 0);
}

// ---------------- prep: fold s (and 1/sqrt(C) into layer 3) into W, cast bf16 ----------------
// Also builds W24 = concat(W2', W4') rows for the merged fo0+fd0 GEMM.
__global__ void prep_weights_k(const float* __restrict__ W, const float* __restrict__ s,
                               const float* __restrict__ b, bf16* __restrict__ Wb,
                               float* __restrict__ bb, bf16* __restrict__ W24,
                               float* __restrict__ b24) {
  int idx = blockIdx.x * 256 + threadIdx.x;     // 7*512*512 threads
  int c = idx & 511;
  int o = (idx >> 9) & 511;
  int l = idx >> 18;
  const float r = 0.04419417382415922f;         // 1/sqrt(512), folded into f_object layer 2 (idx 3)
  float f = (l == 3) ? r : 1.0f;
  float wv = W[idx] * s[(l << 9) + o] * f;
  float bv = b[(l << 9) + o] * f;
  Wb[idx] = (bf16)wv;
  if (c == 0) bb[(l << 9) + o] = bv;
  if (l == 2) { W24[(size_t)o * 512 + c] = (bf16)wv;         if (c == 0) b24[o] = bv; }
  if (l == 4) { W24[(size_t)(512 + o) * 512 + c] = (bf16)wv; if (c == 0) b24[512 + o] = bv; }
}

// ---------------- transpose + cast: in [z][R][S] f32 -> out [z][S][R] bf16 ----------------
// 64x64 tile, float4 loads, bf16x4 stores. R%64==0, S%64==0.
__global__ void transpose_cast_k(const float* __restrict__ in, bf16* __restrict__ out,
                                 int R, int S) {
  __shared__ float tile[64][65];
  int s0 = blockIdx.x * 64, r0 = blockIdx.y * 64;
  size_t zo = (size_t)blockIdx.z * R * S;
  int t = threadIdx.x;          // 256
  int rr = t >> 4, cc = t & 15;
#pragma unroll
  for (int i = 0; i < 4; i++) {
    float4 v = *(const float4*)&in[zo + (size_t)(r0 + rr + 16 * i) * S + s0 + cc * 4];
    tile[rr + 16 * i][cc * 4 + 0] = v.x;
    tile[rr + 16 * i][cc * 4 + 1] = v.y;
    tile[rr + 16 * i][cc * 4 + 2] = v.z;
    tile[rr + 16 * i][cc * 4 + 3] = v.w;
  }
  __syncthreads();
#pragma unroll
  for (int i = 0; i < 4; i++) {
    int sR = rr + 16 * i;       // row of out (S dim)
    bf16x4v o;
    o.x = (bf16)tile[cc * 4 + 0][sR];
    o.y = (bf16)tile[cc * 4 + 1][sR];
    o.z = (bf16)tile[cc * 4 + 2][sR];
    o.w = (bf16)tile[cc * 4 + 3][sR];
    *(bf16x4v*)&out[zo + (size_t)(s0 + sR) * R + r0 + cc * 4] = o;
  }
}

// ---------------- generic NT GEMM (m97 structure) ----------------
// A: [z][M][.] row-stride lda (K contig), B: [z][N][.] row-stride ldb (K contig),
// OUT: [z][M][N] (N contig). OUT = act(A.B^T + bias).
// BIASMODE: 0 none, 1 bias[n], 2 bias[m].
template <bool RELU, bool OUTF32, int BIASMODE>
__global__ __launch_bounds__(256, 2) void gemm_nt(
    const bf16* __restrict__ A, long sAb, int lda,
    const bf16* __restrict__ B, long sBb, int ldb,
    void* __restrict__ OUT, long sOb,
    const float* __restrict__ bias,
    int M, int N, int Kd) {
  __shared__ bf16 sA[128][64];
  __shared__ bf16 sB[128][64];
  const int n0 = blockIdx.x * 128;
  const int m0 = blockIdx.y * 128;
  const bf16* Ab = A + (size_t)blockIdx.z * sAb;
  const bf16* Bb = B + (size_t)blockIdx.z * sBb;
  const int t = threadIdx.x;
  const int lane = t & 63;
  const int w = t >> 6;
  const int wm = (w & 1) << 6;
  const int wn = (w >> 1) << 6;
  const int srow = t >> 3;
  const int scol = (t & 7) << 3;

  f32x4 acc[4][4] = {};
  const int fr = lane & 15;
  const int fq = (lane >> 4) << 3;

  for (int k0 = 0; k0 < Kd; k0 += 64) {
#pragma unroll
    for (int i = 0; i < 4; i++) {
      g2lds16(Ab + (size_t)(m0 + i * 32 + srow) * lda + (k0 + scol), &sA[i * 32 + srow][scol]);
      g2lds16(Bb + (size_t)(n0 + i * 32 + srow) * ldb + (k0 + scol), &sB[i * 32 + srow][scol]);
    }
    __syncthreads();
#pragma unroll
    for (int kk = 0; kk < 64; kk += 32) {
      bf16x8 af[4], bfv[4];
#pragma unroll
      for (int i = 0; i < 4; i++) af[i] = *(const bf16x8*)&sA[wm + i * 16 + fr][kk + fq];
#pragma unroll
      for (int j = 0; j < 4; j++) bfv[j] = *(const bf16x8*)&sB[wn + j * 16 + fr][kk + fq];
#pragma unroll
      for (int i = 0; i < 4; i++)
#pragma unroll
        for (int j = 0; j < 4; j++)
          acc[i][j] = __builtin_amdgcn_mfma_f32_16x16x32_bf16(af[i], bfv[j], acc[i][j], 0, 0, 0);
    }
    __syncthreads();
  }

  const int rb = m0 + wm + ((lane >> 4) << 2);
  const int cb = n0 + wn + (lane & 15);
#pragma unroll
  for (int i = 0; i < 4; i++) {
#pragma unroll
    for (int r = 0; r < 4; r++) {
      const int orow = rb + i * 16 + r;
#pragma unroll
      for (int j = 0; j < 4; j++) {
        const int oc = cb + j * 16;
        float vv = acc[i][j][r];
        if (BIASMODE == 1) vv += bias[oc];
        else if (BIASMODE == 2) vv += bias[orow];
        if (RELU) vv = fmaxf(vv, 0.0f);
        if (OUTF32)
          ((float*)OUT)[(size_t)blockIdx.z * sOb + (size_t)orow * N + oc] = vv;
        else
          ((bf16*)OUT)[(size_t)blockIdx.z * sOb + (size_t)orow * N + oc] = (bf16)vv;
      }
    }
  }
}

// ---------------- fused attention: sim = Q.Key^T -> softmax -> ctx = P.V^T ----------------
// Q [z][HW][512], Key [z][256][512] (scale prefolded), V [z][512][256], CTX [z][HW][512].
// Block: 64 q-rows, all 256 regions. 4 waves, each owns 16 q-rows.
__global__ __launch_bounds__(256, 2) void flash_attn_k(
    const bf16* __restrict__ Q, const bf16* __restrict__ Key,
    const bf16* __restrict__ V, bf16* __restrict__ CTX) {
  __shared__ char smraw[65536];
  bf16 (*sq)[64]    = (bf16(*)[64])smraw;              // phase1: 8 KB
  bf16 (*skey)[64]  = (bf16(*)[64])(smraw + 8192);     // phase1: 32 KB
  bf16 (*sP)[256]   = (bf16(*)[256])smraw;             // phase3: 32 KB (aliases sq/skey)
  bf16 (*sv)[256]   = (bf16(*)[256])(smraw + 32768);   // phase3: 32 KB

  const int t = threadIdx.x;
  const int lane = t & 63;
  const int w = t >> 6;
  const int m0 = blockIdx.x * 64;
  const size_t zq = (size_t)blockIdx.y * 16384 * 512;
  const size_t zk = (size_t)blockIdx.y * 256 * 512;
  const bf16* Qz = Q + zq;
  const bf16* Kz = Key + zk;
  const bf16* Vz = V + zk;            // [512][256] -> same elem count
  bf16* Cz = CTX + zq;

  const int fr = lane & 15;
  const int quad = lane >> 4;
  const int fq = quad << 3;

  // ---- phase 1: S = Q.Key^T, K=512 ----
  f32x4 accS[16] = {};
  {
    const int srow = t >> 3;          // 32 rows per issue, 8 chunks/row
    const int scol = (t & 7) << 3;
    for (int k0 = 0; k0 < 512; k0 += 64) {
#pragma unroll
      for (int i = 0; i < 2; i++)
        g2lds16(Qz + (size_t)(m0 + i * 32 + srow) * 512 + k0 + scol, &sq[i * 32 + srow][scol]);
#pragma unroll
      for (int i = 0; i < 8; i++)
        g2lds16(Kz + (size_t)(i * 32 + srow) * 512 + k0 + scol, &skey[i * 32 + srow][scol]);
      __syncthreads();
#pragma unroll
      for (int kk = 0; kk < 64; kk += 32) {
        bf16x8 aq = *(const bf16x8*)&sq[w * 16 + fr][kk + fq];
#pragma unroll
        for (int j = 0; j < 16; j++) {
          bf16x8 bk = *(const bf16x8*)&skey[j * 16 + fr][kk + fq];
          accS[j] = __builtin_amdgcn_mfma_f32_16x16x32_bf16(aq, bk, accS[j], 0, 0, 0);
        }
      }
      __syncthreads();
    }
  }

  // ---- phase 2: in-register softmax over 256 cols per row ----
  // lane holds rows quad*4+r (within wave's 16), col 16j + (lane&15)
#pragma unroll
  for (int r = 0; r < 4; r++) {
    float m = accS[0][r];
#pragma unroll
    for (int j = 1; j < 16; j++) m = fmaxf(m, accS[j][r]);
#pragma unroll
    for (int o = 1; o < 16; o <<= 1) m = fmaxf(m, __shfl_xor(m, o));
    float sum = 0.0f;
#pragma unroll
    for (int j = 0; j < 16; j++) { float e = __expf(accS[j][r] - m); accS[j][r] = e; sum += e; }
#pragma unroll
    for (int o = 1; o < 16; o <<= 1) sum += __shfl_xor(sum, o);
    float inv = 1.0f / sum;
#pragma unroll
    for (int j = 0; j < 16; j++) accS[j][r] *= inv;
  }

  // write P to LDS (own wave's 16 rows); phase-1 LDS fully drained by trailing barrier above
#pragma unroll
  for (int j = 0; j < 16; j++)
#pragma unroll
    for (int r = 0; r < 4; r++)
      sP[w * 16 + quad * 4 + r][j * 16 + fr] = (bf16)accS[j][r];

  // ---- phase 3: ctx = P.V^T, K=256, loop c-chunks of 64 ----
  {
    const int srow = t >> 5;          // 8 rows per issue, 32 chunks/row
    const int scol = (t & 31) << 3;
    for (int c0 = 0; c0 < 512; c0 += 64) {
#pragma unroll
      for (int i = 0; i < 8; i++)
        g2lds16(Vz + (size_t)(c0 + i * 8 + srow) * 256 + scol, &sv[i * 8 + srow][scol]);
      __syncthreads();
      f32x4 accC[4] = {};
#pragma unroll
      for (int kk = 0; kk < 256; kk += 32) {
        bf16x8 ap = *(const bf16x8*)&sP[w * 16 + fr][kk + fq];
#pragma unroll
        for (int j = 0; j < 4; j++) {
          bf16x8 bv = *(const bf16x8*)&sv[j * 16 + fr][kk + fq];
          accC[j] = __builtin_amdgcn_mfma_f32_16x16x32_bf16(ap, bv, accC[j], 0, 0, 0);
        }
      }
#pragma unroll
      for (int j = 0; j < 4; j++)
#pragma unroll
        for (int r = 0; r < 4; r++)
          Cz[(size_t)(m0 + w * 16 + quad * 4 + r) * 512 + c0 + j * 16 + fr] = (bf16)accC[j][r];
      __syncthreads();
    }
  }
}

extern "C" void kernel_launch(void* const* d_in, const int* in_sizes, int n_in,
                              void* d_out, int out_size, void* d_ws, size_t ws_size,
                              hipStream_t stream) {
  const float* x = (const float*)d_in[0];      // [8, 512, 128, 128]
  const float* proxy = (const float*)d_in[1];  // [8, 512, 256]
  const float* W = (const float*)d_in[2];      // [7, 512, 512]
  const float* s = (const float*)d_in[3];      // [7, 512]
  const float* b = (const float*)d_in[4];      // [7, 512]
  float* out = (float*)d_out;                  // [8, 512, 16384] fp32

  const int C = 512, K = 256, NB = 8, HW = 16384;
  const size_t MiB = 1024 * 1024;
  char* ws = (char*)d_ws;
  if (ws_size < 272 * MiB) return;

  bf16* Wb   = (bf16*)(ws + 0);            // 3.5 MiB
  float* bb  = (float*)(ws + 3670016);
  bf16* W24  = (bf16*)(ws + 4 * MiB);      // [1024][512] = 1 MiB
  float* b24 = (float*)(ws + 5 * MiB);
  bf16* pT   = (bf16*)(ws + 6 * MiB);      // [8][256][512]
  bf16* kt   = (bf16*)(ws + 8 * MiB);      // [8][256][1024]: cols 0-511 k1, 512-1023 t2
  bf16* key  = (bf16*)(ws + 12 * MiB);     // [8][256][512] (1/sqrt(C) folded)
  bf16* v    = (bf16*)(ws + 14 * MiB);     // [8][512][256] value^T
  bf16* bufA = (bf16*)(ws + 16 * MiB);     // 128 MiB: xb -> q
  bf16* bufB = (bf16*)(ws + 144 * MiB);    // 128 MiB: t0 -> ctx

  bf16* xb  = bufA;
  bf16* t0  = bufB;
  bf16* q   = bufA;   // overwrites xb (dead after fp0)
  bf16* ctx = bufB;   // overwrites t0 (dead after fp1)

  const long KC = (long)K * C;       // 131072
  const long KT = (long)K * 1024;    // 262144
  const long HWC = (long)HW * C;     // 8388608

  // 1. fold scales into weights (+ build W24 concat)
  prep_weights_k<<<7 * 512 * 512 / 256, 256, 0, stream>>>(W, s, b, Wb, bb, W24, b24);
  // 2. transpose+cast proxy [z,C,K] -> pT [z,K,C]
  transpose_cast_k<<<dim3(K / 64, C / 64, NB), 256, 0, stream>>>(proxy, pT, C, K);
  // 3. transpose+cast x [z,C,HW] -> xb [z,HW,C]
  transpose_cast_k<<<dim3(HW / 64, C / 64, NB), 256, 0, stream>>>(x, xb, C, HW);
  // 4. merged fo0+fd0: kt = relu(pT.W24^T + b24), N=1024
  gemm_nt<true, false, 1><<<dim3(1024 / 128, K / 128, NB), 256, 0, stream>>>(
      pT, KC, C, W24, 0, C, kt, KT, b24, K, 1024, C);
  // 5. fo1: key = relu(k1.W3'^T + b3')
  gemm_nt<true, false, 1><<<dim3(C / 128, K / 128, NB), 256, 0, stream>>>(
      kt, KT, 1024, Wb + 3 * 262144, 0, C, key, KC, bb + 3 * 512, K, C, C);
  // 6. fd1 (swapped): v[c][k] = relu(W5'.t2^T + b5)
  gemm_nt<true, false, 2><<<dim3(K / 128, C / 128, NB), 256, 0, stream>>>(
      Wb + 5 * 262144, 0, C, kt + 512, KT, 1024, v, KC, bb + 5 * 512, C, K, C);
  // 7. fp0: t0 = relu(xb.W0^T + b0)
  gemm_nt<true, false, 1><<<dim3(C / 128, HW / 128, NB), 256, 0, stream>>>(
      xb, HWC, C, Wb, 0, C, t0, HWC, bb, HW, C, C);
  // 8. fp1: q = relu(t0.W1^T + b1)
  gemm_nt<true, false, 1><<<dim3(C / 128, HW / 128, NB), 256, 0, stream>>>(
      t0, HWC, C, Wb + 1 * 262144, 0, C, q, HWC, bb + 512, HW, C, C);
  // 9. fused attention: ctx = softmax(q.key^T).v^T
  flash_attn_k<<<dim3(HW / 64, NB), 256, 0, stream>>>(q, key, v, ctx);
  // 10. fup (swapped): out[c][hw] = relu(W6'.ctx^T + b6), fp32
  gemm_nt<true, true, 2><<<dim3(HW / 128, C / 128, NB), 256, 0, stream>>>(
      Wb + 6 * 262144, 0, C, ctx, HWC, C, out, HWC, bb + 6 * 512, C, HW, C);
}

// Round 3
// 956.901 us; speedup vs baseline: 1.1288x; 1.1288x over previous
//
#include <hip/hip_runtime.h>
#include <hip/hip_bf16.h>
#include <stdint.h>

typedef __bf16 bf16;
typedef __bf16 bf16x8 __attribute__((ext_vector_type(8)));
typedef __bf16 bf16x4v __attribute__((ext_vector_type(4)));
typedef float f32x4 __attribute__((ext_vector_type(4)));

#define AS1 __attribute__((address_space(1)))
#define AS3 __attribute__((address_space(3)))

__device__ __forceinline__ void g2lds16(const bf16* g, bf16* l) {
  // global -> LDS async copy, 16 B/lane. LDS dest must be wave-uniform base + lane*16.
  __builtin_amdgcn_global_load_lds((AS1 void*)(uintptr_t)g, (AS3 void*)l, 16, 0, 0);
}

// ---------------- prep: fold s (and 1/sqrt(C) into layer 3) into W, cast bf16 ----------------
// Also builds W24 = concat(W2', W4') rows for the merged fo0+fd0 GEMM.
__global__ void prep_weights_k(const float* __restrict__ W, const float* __restrict__ s,
                               const float* __restrict__ b, bf16* __restrict__ Wb,
                               float* __restrict__ bb, bf16* __restrict__ W24,
                               float* __restrict__ b24) {
  int idx = blockIdx.x * 256 + threadIdx.x;     // 7*512*512 threads
  int c = idx & 511;
  int o = (idx >> 9) & 511;
  int l = idx >> 18;
  const float r = 0.04419417382415922f;         // 1/sqrt(512), folded into f_object layer 2 (idx 3)
  float f = (l == 3) ? r : 1.0f;
  float wv = W[idx] * s[(l << 9) + o] * f;
  float bv = b[(l << 9) + o] * f;
  Wb[idx] = (bf16)wv;
  if (c == 0) bb[(l << 9) + o] = bv;
  if (l == 2) { W24[(size_t)o * 512 + c] = (bf16)wv;         if (c == 0) b24[o] = bv; }
  if (l == 4) { W24[(size_t)(512 + o) * 512 + c] = (bf16)wv; if (c == 0) b24[512 + o] = bv; }
}

// ---------------- transpose + cast: in [z][R][S] f32 -> out [z][S][R] bf16 ----------------
// 64x64 tile, float4 loads, bf16x4 stores. R%64==0, S%64==0.
__global__ void transpose_cast_k(const float* __restrict__ in, bf16* __restrict__ out,
                                 int R, int S) {
  __shared__ float tile[64][65];
  int s0 = blockIdx.x * 64, r0 = blockIdx.y * 64;
  size_t zo = (size_t)blockIdx.z * R * S;
  int t = threadIdx.x;          // 256
  int rr = t >> 4, cc = t & 15;
#pragma unroll
  for (int i = 0; i < 4; i++) {
    float4 v = *(const float4*)&in[zo + (size_t)(r0 + rr + 16 * i) * S + s0 + cc * 4];
    tile[rr + 16 * i][cc * 4 + 0] = v.x;
    tile[rr + 16 * i][cc * 4 + 1] = v.y;
    tile[rr + 16 * i][cc * 4 + 2] = v.z;
    tile[rr + 16 * i][cc * 4 + 3] = v.w;
  }
  __syncthreads();
#pragma unroll
  for (int i = 0; i < 4; i++) {
    int sR = rr + 16 * i;       // row of out (S dim)
    bf16x4v o;
    o.x = (bf16)tile[cc * 4 + 0][sR];
    o.y = (bf16)tile[cc * 4 + 1][sR];
    o.z = (bf16)tile[cc * 4 + 2][sR];
    o.w = (bf16)tile[cc * 4 + 3][sR];
    *(bf16x4v*)&out[zo + (size_t)(s0 + sR) * R + r0 + cc * 4] = o;
  }
}

// ---------------- generic NT GEMM (m97 structure) ----------------
// A: [z][M][.] row-stride lda (K contig), B: [z][N][.] row-stride ldb (K contig),
// OUT: [z][M][N] (N contig). OUT = act(A.B^T + bias).
// BIASMODE: 0 none, 1 bias[n], 2 bias[m].
template <bool RELU, bool OUTF32, int BIASMODE>
__global__ __launch_bounds__(256, 2) void gemm_nt(
    const bf16* __restrict__ A, long sAb, int lda,
    const bf16* __restrict__ B, long sBb, int ldb,
    void* __restrict__ OUT, long sOb,
    const float* __restrict__ bias,
    int M, int N, int Kd) {
  __shared__ bf16 sA[128][64];
  __shared__ bf16 sB[128][64];
  const int n0 = blockIdx.x * 128;
  const int m0 = blockIdx.y * 128;
  const bf16* Ab = A + (size_t)blockIdx.z * sAb;
  const bf16* Bb = B + (size_t)blockIdx.z * sBb;
  const int t = threadIdx.x;
  const int lane = t & 63;
  const int w = t >> 6;
  const int wm = (w & 1) << 6;
  const int wn = (w >> 1) << 6;
  const int srow = t >> 3;
  const int scol = (t & 7) << 3;

  f32x4 acc[4][4] = {};
  const int fr = lane & 15;
  const int fq = (lane >> 4) << 3;

  for (int k0 = 0; k0 < Kd; k0 += 64) {
#pragma unroll
    for (int i = 0; i < 4; i++) {
      g2lds16(Ab + (size_t)(m0 + i * 32 + srow) * lda + (k0 + scol), &sA[i * 32 + srow][scol]);
      g2lds16(Bb + (size_t)(n0 + i * 32 + srow) * ldb + (k0 + scol), &sB[i * 32 + srow][scol]);
    }
    __syncthreads();
#pragma unroll
    for (int kk = 0; kk < 64; kk += 32) {
      bf16x8 af[4], bfv[4];
#pragma unroll
      for (int i = 0; i < 4; i++) af[i] = *(const bf16x8*)&sA[wm + i * 16 + fr][kk + fq];
#pragma unroll
      for (int j = 0; j < 4; j++) bfv[j] = *(const bf16x8*)&sB[wn + j * 16 + fr][kk + fq];
#pragma unroll
      for (int i = 0; i < 4; i++)
#pragma unroll
        for (int j = 0; j < 4; j++)
          acc[i][j] = __builtin_amdgcn_mfma_f32_16x16x32_bf16(af[i], bfv[j], acc[i][j], 0, 0, 0);
    }
    __syncthreads();
  }

  const int rb = m0 + wm + ((lane >> 4) << 2);
  const int cb = n0 + wn + (lane & 15);
#pragma unroll
  for (int i = 0; i < 4; i++) {
#pragma unroll
    for (int r = 0; r < 4; r++) {
      const int orow = rb + i * 16 + r;
#pragma unroll
      for (int j = 0; j < 4; j++) {
        const int oc = cb + j * 16;
        float vv = acc[i][j][r];
        if (BIASMODE == 1) vv += bias[oc];
        else if (BIASMODE == 2) vv += bias[orow];
        if (RELU) vv = fmaxf(vv, 0.0f);
        if (OUTF32)
          ((float*)OUT)[(size_t)blockIdx.z * sOb + (size_t)orow * N + oc] = vv;
        else
          ((bf16*)OUT)[(size_t)blockIdx.z * sOb + (size_t)orow * N + oc] = (bf16)vv;
      }
    }
  }
}

// ---------------- sim + softmax fused: P = softmax_rows(Q.Key^T) ----------------
// Q [z][16384][512], Key [z][256][512] (1/sqrt(C) prefolded), P [z][16384][256] bf16.
// Block = 128 q-rows x all 256 regions; wave owns 32 rows x 256 cols -> full row
// in-register => epilogue softmax needs only in-lane + intra-quad shfl reductions.
__global__ __launch_bounds__(256, 2) void sim_softmax_k(
    const bf16* __restrict__ Q, const bf16* __restrict__ Key, bf16* __restrict__ P) {
  __shared__ bf16 sQ[128][64];   // 16 KB
  __shared__ bf16 sK[256][64];   // 32 KB
  const int t = threadIdx.x;
  const int lane = t & 63;
  const int w = t >> 6;
  const int m0 = blockIdx.x * 128;
  const bf16* Qz = Q + (size_t)blockIdx.y * 16384 * 512;
  const bf16* Kz = Key + (size_t)blockIdx.y * 256 * 512;
  bf16* Pz = P + (size_t)blockIdx.y * 16384 * 256;

  const int fr = lane & 15;
  const int quad = lane >> 4;
  const int fq = quad << 3;
  const int wm = w << 5;            // wave's 32 q-rows
  const int srow = t >> 3;          // staging: 32 rows/issue, 8x16B chunks per row
  const int scol = (t & 7) << 3;

  f32x4 acc[2][16] = {};

  for (int k0 = 0; k0 < 512; k0 += 64) {
#pragma unroll
    for (int i = 0; i < 4; i++)
      g2lds16(Qz + (size_t)(m0 + i * 32 + srow) * 512 + k0 + scol, &sQ[i * 32 + srow][scol]);
#pragma unroll
    for (int i = 0; i < 8; i++)
      g2lds16(Kz + (size_t)(i * 32 + srow) * 512 + k0 + scol, &sK[i * 32 + srow][scol]);
    __syncthreads();
#pragma unroll
    for (int kk = 0; kk < 64; kk += 32) {
      bf16x8 aq0 = *(const bf16x8*)&sQ[wm + fr][kk + fq];
      bf16x8 aq1 = *(const bf16x8*)&sQ[wm + 16 + fr][kk + fq];
#pragma unroll
      for (int j = 0; j < 16; j++) {
        bf16x8 bk = *(const bf16x8*)&sK[j * 16 + fr][kk + fq];
        acc[0][j] = __builtin_amdgcn_mfma_f32_16x16x32_bf16(aq0, bk, acc[0][j], 0, 0, 0);
        acc[1][j] = __builtin_amdgcn_mfma_f32_16x16x32_bf16(aq1, bk, acc[1][j], 0, 0, 0);
      }
    }
    __syncthreads();
  }

  // epilogue: softmax per row. Row wm+i*16+quad*4+r lives in the 16 lanes of this
  // quad (fr=0..15), 16 cols each (j*16+fr). Reduce in-lane over j, then shfl 1/2/4/8.
#pragma unroll
  for (int i = 0; i < 2; i++) {
#pragma unroll
    for (int r = 0; r < 4; r++) {
      float m = acc[i][0][r];
#pragma unroll
      for (int j = 1; j < 16; j++) m = fmaxf(m, acc[i][j][r]);
#pragma unroll
      for (int o = 1; o < 16; o <<= 1) m = fmaxf(m, __shfl_xor(m, o));
      float sum = 0.0f;
#pragma unroll
      for (int j = 0; j < 16; j++) {
        float e = __expf(acc[i][j][r] - m);
        acc[i][j][r] = e;
        sum += e;
      }
#pragma unroll
      for (int o = 1; o < 16; o <<= 1) sum += __shfl_xor(sum, o);
      float inv = 1.0f / sum;
      const size_t rowoff = (size_t)(m0 + wm + i * 16 + (quad << 2) + r) * 256;
#pragma unroll
      for (int j = 0; j < 16; j++)
        Pz[rowoff + j * 16 + fr] = (bf16)(acc[i][j][r] * inv);
    }
  }
}

extern "C" void kernel_launch(void* const* d_in, const int* in_sizes, int n_in,
                              void* d_out, int out_size, void* d_ws, size_t ws_size,
                              hipStream_t stream) {
  const float* x = (const float*)d_in[0];      // [8, 512, 128, 128]
  const float* proxy = (const float*)d_in[1];  // [8, 512, 256]
  const float* W = (const float*)d_in[2];      // [7, 512, 512]
  const float* s = (const float*)d_in[3];      // [7, 512]
  const float* b = (const float*)d_in[4];      // [7, 512]
  float* out = (float*)d_out;                  // [8, 512, 16384] fp32

  const int C = 512, K = 256, NB = 8, HW = 16384;
  const size_t MiB = 1024 * 1024;
  char* ws = (char*)d_ws;
  if (ws_size < 272 * MiB) return;

  bf16* Wb   = (bf16*)(ws + 0);            // 3.5 MiB
  float* bb  = (float*)(ws + 3670016);
  bf16* W24  = (bf16*)(ws + 4 * MiB);      // [1024][512] = 1 MiB
  float* b24 = (float*)(ws + 5 * MiB);
  bf16* pT   = (bf16*)(ws + 6 * MiB);      // [8][256][512]
  bf16* kt   = (bf16*)(ws + 8 * MiB);      // [8][256][1024]: cols 0-511 k1, 512-1023 t2
  bf16* key  = (bf16*)(ws + 12 * MiB);     // [8][256][512] (1/sqrt(C) folded)
  bf16* v    = (bf16*)(ws + 14 * MiB);     // [8][512][256] value^T
  bf16* bufA = (bf16*)(ws + 16 * MiB);     // 128 MiB: xb -> q -> ctx
  bf16* bufB = (bf16*)(ws + 144 * MiB);    // 128 MiB: t0 -> P

  bf16* xb  = bufA;
  bf16* t0  = bufB;
  bf16* q   = bufA;   // overwrites xb (dead after fp0)
  bf16* P   = bufB;   // overwrites t0 (dead after fp1)
  bf16* ctx = bufA;   // overwrites q  (dead after sim)

  const long KC = (long)K * C;       // 131072
  const long KT = (long)K * 1024;    // 262144
  const long HWC = (long)HW * C;     // 8388608
  const long HWK = (long)HW * K;     // 4194304

  // 1. fold scales into weights (+ build W24 concat)
  prep_weights_k<<<7 * 512 * 512 / 256, 256, 0, stream>>>(W, s, b, Wb, bb, W24, b24);
  // 2. transpose+cast proxy [z,C,K] -> pT [z,K,C]
  transpose_cast_k<<<dim3(K / 64, C / 64, NB), 256, 0, stream>>>(proxy, pT, C, K);
  // 3. transpose+cast x [z,C,HW] -> xb [z,HW,C]
  transpose_cast_k<<<dim3(HW / 64, C / 64, NB), 256, 0, stream>>>(x, xb, C, HW);
  // 4. merged fo0+fd0: kt = relu(pT.W24^T + b24), N=1024
  gemm_nt<true, false, 1><<<dim3(1024 / 128, K / 128, NB), 256, 0, stream>>>(
      pT, KC, C, W24, 0, C, kt, KT, b24, K, 1024, C);
  // 5. fo1: key = relu(k1.W3'^T + b3')
  gemm_nt<true, false, 1><<<dim3(C / 128, K / 128, NB), 256, 0, stream>>>(
      kt, KT, 1024, Wb + 3 * 262144, 0, C, key, KC, bb + 3 * 512, K, C, C);
  // 6. fd1 (swapped): v[c][k] = relu(W5'.t2^T + b5)
  gemm_nt<true, false, 2><<<dim3(K / 128, C / 128, NB), 256, 0, stream>>>(
      Wb + 5 * 262144, 0, C, kt + 512, KT, 1024, v, KC, bb + 5 * 512, C, K, C);
  // 7. fp0: t0 = relu(xb.W0^T + b0)
  gemm_nt<true, false, 1><<<dim3(C / 128, HW / 128, NB), 256, 0, stream>>>(
      xb, HWC, C, Wb, 0, C, t0, HWC, bb, HW, C, C);
  // 8. fp1: q = relu(t0.W1^T + b1)
  gemm_nt<true, false, 1><<<dim3(C / 128, HW / 128, NB), 256, 0, stream>>>(
      t0, HWC, C, Wb + 1 * 262144, 0, C, q, HWC, bb + 512, HW, C, C);
  // 9. sim + softmax fused: P = softmax(q.key^T)
  sim_softmax_k<<<dim3(HW / 128, NB), 256, 0, stream>>>(q, key, P);
  // 10. ctx = P.v^T  [z][HW][512]
  gemm_nt<false, false, 0><<<dim3(C / 128, HW / 128, NB), 256, 0, stream>>>(
      P, HWK, K, v, KC, K, ctx, HWC, nullptr, HW, C, K);
  // 11. fup (swapped): out[c][hw] = relu(W6'.ctx^T + b6), fp32
  gemm_nt<true, true, 2><<<dim3(HW / 128, C / 128, NB), 256, 0, stream>>>(
      Wb + 6 * 262144, 0, C, ctx, HWC, C, out, HWC, bb + 6 * 512, C, HW, C);
}